// Round 4
// baseline (153.509 us; speedup 1.0000x reference)
//
#include <hip/hip_runtime.h>

// SAGE layer: out = relu(x @ W_self + (segment_sum(x[src], dst)/max(deg,1)) @ W_neigh + b)
//
// R17 = R16 with aggregate+GEMM fused (k_aggemm):
//   - k_agg block (b,q) owns rows [b*256+q*64, +64) == exactly one GEMM tile.
//     Gather means go to a 64x72 LDS tile (hbt) instead of global hb; the
//     16x16x32 MFMA tile consumes hbt (k 64..127) + direct xb loads (k 0..63).
//   - kills hb write (12.8MB) + hb read (12.8MB) + one dispatch.
//   - scsr shrunk to a union with the W LDS tile (quarter slice = 640+-25
//     edges, 4352 capacity; W staged into the union AFTER the gather
//     barrier). LDS ~27.5KB -> 5 blocks/CU, keeps gather-phase waves high.
// Failed-experiment log (do not repeat):
//   R4: LDS float atomicAdd = CAS loops -> 448us.  R6: 1-block serial scan -> 121us.
//   R8: gather fused into GEMM blocks (TLP/16) -> 70us kernel.
//   R10: per-block O(c) serial prefix + fixed-stride regions -> k_place 44.5us.
//   R11: wider (16B) gather loads, same MLP -> neutral.
//   R13: dual-row aggregate -> 170us; k_place+k_csr ~70us combined.
//   R14: slotted CSR via 1M returning global atomics + 4B scatter -> k_conv
//        100us (WRITE 72MB = 16x amplification). NEVER random sub-line global
//        scatter at this edge count.
//   R15: CSR+aggregate merged into 391 one-per-bucket blocks -> occ 25%,
//        latency-starved gather, 61us. Resident waves are the scarce resource.
//   R16: 4 blocks/bucket + group-per-row (no shfl epilogue) -> 151us total. WIN.
// Pipeline (5 dispatches, zero global atomics, zero memsets on main path):
//   1. k_conv   2. k_scanA  3. k_scanB  4. k_place  5. k_aggemm
// Fallback (small ws): R0 scatter + shfl gemm.

constexpr int F = 64;
constexpr int BROWS = 256;   // dst rows per bucket
constexpr int MAXNB = 512;   // max buckets (num_dst <= 131072)
constexpr int CHP = 4096;    // edges per chunk
constexpr int LDK = 136;     // 128 + 8 pad (bf16 elems) for W tile
constexpr int QCAP = 4352;   // scsr capacity (union bytes / 4)
constexpr int LDH = 72;      // hbt row pitch (64 + 8 pad)

typedef __attribute__((ext_vector_type(8))) short short8;
typedef __attribute__((ext_vector_type(4))) float float4v;

__device__ inline unsigned short f2bf(float f) {
    union { float f; unsigned u; } c; c.f = f;
    unsigned u = c.u;
    return (unsigned short)((u + 0x7FFFu + ((u >> 16) & 1u)) >> 16);  // RNE
}
__device__ inline float bf2f(unsigned short h) {
    union { unsigned u; float f; } c; c.u = (unsigned)h << 16;
    return c.f;
}

// ---------------- 1. x->bf16 + W->bf16^T + per-chunk bucket counts ----------------
__global__ __launch_bounds__(256) void k_conv(const float* __restrict__ x,
                                              const float* __restrict__ Ws,
                                              const float* __restrict__ Wn,
                                              unsigned short* __restrict__ xb,
                                              unsigned short* __restrict__ WtG,
                                              const int* __restrict__ dst,
                                              int* __restrict__ cnt,
                                              long n4, int n_edges, int nchunk) {
    __shared__ int hist[MAXNB];
    int t = threadIdx.x;
    long tid = (long)blockIdx.x * 256 + t;
    // W -> bf16 transposed
    if (tid < 2 * F * F) {
        int i = (int)tid;
        int n = i & 63, k = i >> 6;
        float v = (k < 64) ? Ws[k * 64 + n] : Wn[(k - 64) * 64 + n];
        WtG[n * 128 + k] = f2bf(v);
    }
    // chunk histogram (blocks < nchunk)
    int c = blockIdx.x;
    if (c < nchunk) {
        for (int i = t; i < MAXNB; i += 256) hist[i] = 0;
        __syncthreads();
        int e0 = c * CHP, e1 = min(e0 + CHP, n_edges);
        for (int e = e0 + t; e < e1; e += 256) atomicAdd(&hist[dst[e] >> 8], 1);
        __syncthreads();
        for (int i = t; i < MAXNB; i += 256) cnt[(long)c * MAXNB + i] = hist[i];
    }
    // x -> bf16
    for (long i = tid; i < n4; i += (long)gridDim.x * 256) {
        float4 v = ((const float4*)x)[i];
        ushort4 o;
        o.x = f2bf(v.x); o.y = f2bf(v.y); o.z = f2bf(v.z); o.w = f2bf(v.w);
        ((ushort4*)xb)[i] = o;
    }
}

// ---------------- 2. parallel column scan: wave per bucket ----------------
__global__ __launch_bounds__(512) void k_scanA(int* __restrict__ cnt,   // in-place -> pref
                                               int* __restrict__ btot, int nchunk) {
    int b = (blockIdx.x * 512 + threadIdx.x) >> 6;   // bucket = global wave id
    int lane = threadIdx.x & 63;
    if (b >= MAXNB) return;
    int per = (nchunk + 63) / 64;                    // chunks per lane (<=16 for nchunk<=1024)
    int c0 = lane * per;
    int vals[16];
    int lsum = 0;
#pragma unroll
    for (int i = 0; i < 16; ++i) {
        if (i < per) {
            int c = c0 + i;
            int v = (c < nchunk) ? cnt[(long)c * MAXNB + b] : 0;
            vals[i] = v; lsum += v;
        }
    }
    int incl = lsum;
    for (int off = 1; off < 64; off <<= 1) {
        int o = __shfl_up(incl, off);
        if (lane >= off) incl += o;
    }
    int run = incl - lsum;
#pragma unroll
    for (int i = 0; i < 16; ++i) {
        if (i < per) {
            int c = c0 + i;
            if (c < nchunk) { cnt[(long)c * MAXNB + b] = run; run += vals[i]; }
        }
    }
    int tot = __shfl(incl, 63);
    if (lane == 0) btot[b] = tot;
}

// ---------------- 3. cross-bucket exclusive scan: btot -> bstart (1 block) ----------------
__global__ __launch_bounds__(512) void k_scanB(const int* __restrict__ btot,
                                               int* __restrict__ bstart) {
    __shared__ int wtot[8];
    __shared__ int woff[8];
    int t = threadIdx.x;
    int lane = t & 63, wave = t >> 6;
    int v = btot[t];
    int incl = v;
    for (int off = 1; off < 64; off <<= 1) {
        int o = __shfl_up(incl, off);
        if (lane >= off) incl += o;
    }
    if (lane == 63) wtot[wave] = incl;
    __syncthreads();
    if (t == 0) { int s = 0; for (int i = 0; i < 8; ++i) { woff[i] = s; s += wtot[i]; } }
    __syncthreads();
    bstart[t] = incl - v + woff[wave];
    if (t == 511) bstart[MAXNB] = woff[7] + incl;
}

// ---------------- 4. place edges: LDS counting sort + coalesced flush ----------------
__global__ __launch_bounds__(512) void k_place(const int* __restrict__ src,
                                               const int* __restrict__ dst,
                                               const int* __restrict__ cnt,     // pref
                                               const int* __restrict__ bstart,
                                               unsigned* __restrict__ pay, int n_edges) {
    __shared__ int sbp[MAXNB];       // bstart[b] + pref[b]
    __shared__ int lstart[MAXNB];
    __shared__ int lcur[MAXNB];
    __shared__ unsigned spay[CHP];
    __shared__ int sgpos[CHP];
    __shared__ int wtot[8];
    __shared__ int woff[8];
    int t = threadIdx.x;
    int c = blockIdx.x;
    int e0 = c * CHP, e1 = min(e0 + CHP, n_edges);
    sbp[t] = bstart[t] + cnt[(long)c * MAXNB + t];
    lcur[t] = 0;
    __syncthreads();
    for (int e = e0 + t; e < e1; e += 512) atomicAdd(&lcur[dst[e] >> 8], 1);
    __syncthreads();
    // exclusive scan of lcur via wave-scan + wave-offset combine (2 barriers)
    int lane = t & 63, wave = t >> 6;
    int v = lcur[t];
    int incl = v;
    for (int off = 1; off < 64; off <<= 1) {
        int o = __shfl_up(incl, off);
        if (lane >= off) incl += o;
    }
    if (lane == 63) wtot[wave] = incl;
    __syncthreads();
    if (t == 0) { int s = 0; for (int i = 0; i < 8; ++i) { woff[i] = s; s += wtot[i]; } }
    __syncthreads();
    lstart[t] = incl - v + woff[wave];
    lcur[t] = 0;
    __syncthreads();
    // place sorted into LDS, remember final global position
    for (int e = e0 + t; e < e1; e += 512) {
        int d = dst[e];
        int b = d >> 8;
        int rank = atomicAdd(&lcur[b], 1);
        int idx = lstart[b] + rank;
        spay[idx] = ((unsigned)src[e] << 8) | (unsigned)(d & 255);
        sgpos[idx] = sbp[b] + rank;
    }
    __syncthreads();
    // linear flush: consecutive i -> consecutive pay positions within runs
    int n = e1 - e0;
    for (int i = t; i < n; i += 512) pay[sgpos[i]] = spay[i];
}

// ---------------- 5. fused aggregate + dual-GEMM (4 blocks/bucket) ----------------
__global__ __launch_bounds__(256) void k_aggemm(const unsigned short* __restrict__ xb,
                                                const unsigned* __restrict__ pay,
                                                const int* __restrict__ bstart,
                                                const unsigned short* __restrict__ WtG,
                                                const float* __restrict__ bias,
                                                float* __restrict__ out,
                                                int num_dst) {
    __shared__ int degs[64];
    __shared__ int rs[64];
    __shared__ int cur[64];
    // union: scsr (gather phase) / W tile (MFMA phase)
    __shared__ __align__(16) unsigned char upool[64 * LDK * 2];   // 17408 B
    __shared__ __align__(16) unsigned short hbt[64 * LDH];        // 64 x 64 means, pad 8
    int* scsr = (int*)upool;
    unsigned short* Wt = (unsigned short*)upool;

    int t = threadIdx.x;
    int blk = blockIdx.x;
    int b = blk >> 2, q = blk & 3;     // bucket, quarter
    int grow0 = b * BROWS + q * 64;
    if (grow0 >= num_dst) return;      // whole block beyond output
    int s0 = bstart[b], s1 = bstart[b + 1];
    int lane = t & 63;
    int wave = t >> 6;

    // --- phase 1: quarter histogram + scan + LDS CSR ---
    if (t < 64) degs[t] = 0;
    __syncthreads();
    for (int i = s0 + t; i < s1; i += 256) {
        int row = pay[i] & 255;
        if ((row >> 6) == q) atomicAdd(&degs[row & 63], 1);
    }
    __syncthreads();
    if (t < 64) {
        int v = degs[t];
        int incl = v;
        for (int off = 1; off < 64; off <<= 1) {
            int o = __shfl_up(incl, off);
            if (t >= off) incl += o;
        }
        rs[t] = incl - v;
        cur[t] = incl - v;
    }
    __syncthreads();
    for (int i = s0 + t; i < s1; i += 256) {
        unsigned p = pay[i];
        int row = p & 255;
        if ((row >> 6) == q) {
            int pos = atomicAdd(&cur[row & 63], 1);
            if (pos < QCAP) scsr[pos] = (int)(p >> 8);
        }
    }
    __syncthreads();

    // --- phase 2: group-per-row gather, means -> hbt ---
    int g = lane >> 3;          // group id = row within batch
    int c8 = (lane & 7) * 8;    // feature octet
#pragma unroll
    for (int batch = 0; batch < 2; ++batch) {
        int rl = wave * 16 + batch * 8 + g;        // 0..63
        int deg = degs[rl];
        int base = rs[rl];
        float acc[8] = {0.f, 0.f, 0.f, 0.f, 0.f, 0.f, 0.f, 0.f};
        for (int k = 0; k < deg; k += 4) {
            int dm = deg - 1;
            int i0 = scsr[base + k];
            int i1 = scsr[base + min(k + 1, dm)];
            int i2 = scsr[base + min(k + 2, dm)];
            int i3 = scsr[base + min(k + 3, dm)];
            short8 u0 = *(const short8*)&xb[(long)i0 * F + c8];
            short8 u1 = *(const short8*)&xb[(long)i1 * F + c8];
            short8 u2 = *(const short8*)&xb[(long)i2 * F + c8];
            short8 u3 = *(const short8*)&xb[(long)i3 * F + c8];
#pragma unroll
            for (int j = 0; j < 8; ++j) acc[j] += bf2f((unsigned short)u0[j]);
            if (k + 1 < deg) {
#pragma unroll
                for (int j = 0; j < 8; ++j) acc[j] += bf2f((unsigned short)u1[j]);
            }
            if (k + 2 < deg) {
#pragma unroll
                for (int j = 0; j < 8; ++j) acc[j] += bf2f((unsigned short)u2[j]);
            }
            if (k + 3 < deg) {
#pragma unroll
                for (int j = 0; j < 8; ++j) acc[j] += bf2f((unsigned short)u3[j]);
            }
        }
        float inv = 1.0f / fmaxf((float)deg, 1.0f);
        short8 o;
#pragma unroll
        for (int j = 0; j < 8; ++j) o[j] = (short)f2bf(acc[j] * inv);
        *(short8*)&hbt[rl * LDH + c8] = o;
    }
    __syncthreads();   // scsr dead, hbt complete

    // --- phase 3: stage W into union, then MFMA ---
    for (int i = t; i < 64 * 16; i += 256) {
        int r = i >> 4, s = i & 15;
        *(short8*)&Wt[r * LDK + s * 8] = *(const short8*)&WtG[r * 128 + s * 8];
    }
    __syncthreads();

    int m = lane & 15;
    int quad = lane >> 4;
    // A fragments: kb 0,1 from xb (global, k 0..63); kb 2,3 from hbt (k 64..127)
    int rowg = grow0 + wave * 16 + m;
    int rx = min(rowg, num_dst - 1);
    const unsigned short* xrow = &xb[(long)rx * F + quad * 8];
    short8 a0 = *(const short8*)(xrow);
    short8 a1 = *(const short8*)(xrow + 32);
    const unsigned short* hrow = &hbt[(wave * 16 + m) * LDH + quad * 8];
    short8 a2 = *(const short8*)(hrow);
    short8 a3 = *(const short8*)(hrow + 32);

    float4v acc[4];
#pragma unroll
    for (int nt = 0; nt < 4; ++nt) acc[nt] = (float4v){0.f, 0.f, 0.f, 0.f};

#pragma unroll
    for (int nt = 0; nt < 4; ++nt) {
        const unsigned short* wrow = &Wt[(nt * 16 + m) * LDK + quad * 8];
        short8 b0 = *(const short8*)(wrow);
        short8 b1 = *(const short8*)(wrow + 32);
        short8 b2 = *(const short8*)(wrow + 64);
        short8 b3 = *(const short8*)(wrow + 96);
        acc[nt] = __builtin_amdgcn_mfma_f32_16x16x32_bf16(a0, b0, acc[nt], 0, 0, 0);
        acc[nt] = __builtin_amdgcn_mfma_f32_16x16x32_bf16(a1, b1, acc[nt], 0, 0, 0);
        acc[nt] = __builtin_amdgcn_mfma_f32_16x16x32_bf16(a2, b2, acc[nt], 0, 0, 0);
        acc[nt] = __builtin_amdgcn_mfma_f32_16x16x32_bf16(a3, b3, acc[nt], 0, 0, 0);
    }

    int gr_base = grow0 + wave * 16 + quad * 4;
#pragma unroll
    for (int nt = 0; nt < 4; ++nt) {
        int col = nt * 16 + m;
        float bv = bias[col];
#pragma unroll
        for (int rg = 0; rg < 4; ++rg) {
            int gg = gr_base + rg;
            if (gg < num_dst) out[(long)gg * F + col] = fmaxf(acc[nt][rg] + bv, 0.0f);
        }
    }
}

// ---------------- fallback (R0, proven) ----------------
__global__ __launch_bounds__(256) void k_scatter(const float* __restrict__ x, const int* __restrict__ src,
                                                 const int* __restrict__ dst, float* __restrict__ summed,
                                                 float* __restrict__ degf, int n_edges) {
    long tid = (long)blockIdx.x * 256 + threadIdx.x;
    int e = (int)(tid >> 6);
    if (e >= n_edges) return;
    int f = threadIdx.x & 63;
    atomicAdd(&summed[(long)dst[e] * F + f], x[(long)src[e] * F + f]);
    if (f == 0) atomicAdd(&degf[dst[e]], 1.0f);
}

__global__ __launch_bounds__(256) void k_gemm_shfl(
    const float* __restrict__ x, const float* __restrict__ Ws, const float* __restrict__ Wn,
    const float* __restrict__ b, const float* __restrict__ degf, float* inout, int num_dst)
{
    __shared__ float Wl[2 * F * F];
    for (int i = threadIdx.x; i < F * F; i += 256) { Wl[i] = Ws[i]; Wl[F * F + i] = Wn[i]; }
    __syncthreads();
    int lane = threadIdx.x & 63;
    int r = (blockIdx.x * 256 + threadIdx.x) >> 6;
    if (r >= num_dst) return;
    float xv = x[(long)r * F + lane];
    float hv = inout[(long)r * F + lane] / fmaxf(degf[r], 1.0f);
    float acc = b[lane];
#pragma unroll
    for (int k = 0; k < F; ++k) {
        acc += __shfl(xv, k) * Wl[k * F + lane];
        acc += __shfl(hv, k) * Wl[(F + k) * F + lane];
    }
    inout[(long)r * F + lane] = fmaxf(acc, 0.0f);
}

// ---------------- launch ----------------
extern "C" void kernel_launch(void* const* d_in, const int* in_sizes, int n_in,
                              void* d_out, int out_size, void* d_ws, size_t ws_size,
                              hipStream_t stream) {
    const float* x  = (const float*)d_in[0];
    const float* Ws = (const float*)d_in[1];
    const float* Wn = (const float*)d_in[2];
    const float* b  = (const float*)d_in[3];
    const int* src  = (const int*)d_in[4];
    const int* dst  = (const int*)d_in[5];
    int n_edges = in_sizes[4];
    int num_dst = out_size / F;
    float* out = (float*)d_out;

    int nchunk = (n_edges + CHP - 1) / CHP;
    int nb = (num_dst + BROWS - 1) / BROWS;

    char* ws = (char*)d_ws;
    size_t off = 0;
    auto alloc = [&](size_t bytes) { char* p = ws + off; off = (off + bytes + 255) & ~(size_t)255; return p; };
    unsigned short* xb  = (unsigned short*)alloc((size_t)num_dst * F * 2);
    unsigned* pay       = (unsigned*)alloc((size_t)n_edges * 4);
    unsigned short* WtG = (unsigned short*)alloc(2 * F * F * 2);
    int* cnt            = (int*)alloc((size_t)nchunk * MAXNB * 4);
    int* btot           = (int*)alloc(MAXNB * 4);
    int* bstart         = (int*)alloc((MAXNB + 1) * 4);
    bool big_ws = (off <= ws_size) && (nb <= MAXNB) && (nchunk <= 1024);

    if (big_ws) {
        long n4 = (long)num_dst * F / 4;
        int convgrid = max(2048, nchunk);
        k_conv<<<convgrid, 256, 0, stream>>>(x, Ws, Wn, xb, WtG, dst, cnt, n4, n_edges, nchunk);
        k_scanA<<<(MAXNB * 64 + 511) / 512, 512, 0, stream>>>(cnt, btot, nchunk);
        k_scanB<<<1, 512, 0, stream>>>(btot, bstart);
        k_place<<<nchunk, 512, 0, stream>>>(src, dst, cnt, bstart, pay, n_edges);
        k_aggemm<<<nb * 4, 256, 0, stream>>>(xb, pay, bstart, WtG, b, out, num_dst);
    } else {
        float* degf = (float*)d_ws;
        (void)hipMemsetAsync(d_out, 0, (size_t)out_size * sizeof(float), stream);
        (void)hipMemsetAsync(degf, 0, (size_t)num_dst * sizeof(float), stream);
        long tt = (long)n_edges * 64;
        k_scatter<<<(int)((tt + 255) / 256), 256, 0, stream>>>(x, src, dst, out, degf, n_edges);
        k_gemm_shfl<<<(num_dst + 3) / 4, 256, 0, stream>>>(x, Ws, Wn, b, degf, out, num_dst);
    }
}

// Round 5
// 149.754 us; speedup vs baseline: 1.0251x; 1.0251x over previous
//
#include <hip/hip_runtime.h>

// SAGE layer: out = relu(x @ W_self + (segment_sum(x[src], dst)/max(deg,1)) @ W_neigh + b)
//
// R18 = R17 with latency attacked directly:
//   - k_aggemm gather unrolled 8-deep (was 4): deg~10 -> 2 dependent load
//     batches per row instead of 3; per-lane MLP doubled.
//   - k_place single-pass: rank captured from the histogram atomicAdd, edges
//     held in 16 regs (8/thread, static unroll), replayed after the scan.
//     Kills the second dst read + second LDS atomic pass.
// Failed-experiment log (do not repeat):
//   R4: LDS float atomicAdd = CAS loops -> 448us.  R6: 1-block serial scan -> 121us.
//   R8: gather fused into GEMM blocks (TLP/16) -> 70us kernel.
//   R10: per-block O(c) serial prefix + fixed-stride regions -> k_place 44.5us.
//   R11: wider (16B) gather loads, same MLP -> neutral.
//   R13: dual-row aggregate -> 170us; k_place+k_csr ~70us combined.
//   R14: slotted CSR via 1M returning global atomics + 4B scatter -> k_conv
//        100us (WRITE 72MB = 16x amplification). NEVER random sub-line global
//        scatter at this edge count.
//   R15: CSR+aggregate merged into 391 one-per-bucket blocks -> occ 25%,
//        latency-starved gather, 61us. Resident waves are the scarce resource.
//   R16: 4 blocks/bucket + group-per-row (no shfl epilogue) -> 151us total. WIN.
//   R17: agg+GEMM fused (hb round-trip removed) -> 153.5us, neutral: hb
//        traffic was L2-resident/overlapped; gather still latency-bound
//        (24% HBM, 19% VALU, occ 30%).
// Pipeline (5 dispatches, zero global atomics, zero memsets on main path):
//   1. k_conv   2. k_scanA  3. k_scanB  4. k_place  5. k_aggemm
// Fallback (small ws): R0 scatter + shfl gemm.

constexpr int F = 64;
constexpr int BROWS = 256;   // dst rows per bucket
constexpr int MAXNB = 512;   // max buckets (num_dst <= 131072)
constexpr int CHP = 4096;    // edges per chunk
constexpr int LDK = 136;     // 128 + 8 pad (bf16 elems) for W tile
constexpr int QCAP = 4352;   // scsr capacity (union bytes / 4)
constexpr int LDH = 72;      // hbt row pitch (64 + 8 pad)

typedef __attribute__((ext_vector_type(8))) short short8;
typedef __attribute__((ext_vector_type(4))) float float4v;

__device__ inline unsigned short f2bf(float f) {
    union { float f; unsigned u; } c; c.f = f;
    unsigned u = c.u;
    return (unsigned short)((u + 0x7FFFu + ((u >> 16) & 1u)) >> 16);  // RNE
}
__device__ inline float bf2f(unsigned short h) {
    union { unsigned u; float f; } c; c.u = (unsigned)h << 16;
    return c.f;
}

// ---------------- 1. x->bf16 + W->bf16^T + per-chunk bucket counts ----------------
__global__ __launch_bounds__(256) void k_conv(const float* __restrict__ x,
                                              const float* __restrict__ Ws,
                                              const float* __restrict__ Wn,
                                              unsigned short* __restrict__ xb,
                                              unsigned short* __restrict__ WtG,
                                              const int* __restrict__ dst,
                                              int* __restrict__ cnt,
                                              long n4, int n_edges, int nchunk) {
    __shared__ int hist[MAXNB];
    int t = threadIdx.x;
    long tid = (long)blockIdx.x * 256 + t;
    // W -> bf16 transposed
    if (tid < 2 * F * F) {
        int i = (int)tid;
        int n = i & 63, k = i >> 6;
        float v = (k < 64) ? Ws[k * 64 + n] : Wn[(k - 64) * 64 + n];
        WtG[n * 128 + k] = f2bf(v);
    }
    // chunk histogram (blocks < nchunk)
    int c = blockIdx.x;
    if (c < nchunk) {
        for (int i = t; i < MAXNB; i += 256) hist[i] = 0;
        __syncthreads();
        int e0 = c * CHP, e1 = min(e0 + CHP, n_edges);
        for (int e = e0 + t; e < e1; e += 256) atomicAdd(&hist[dst[e] >> 8], 1);
        __syncthreads();
        for (int i = t; i < MAXNB; i += 256) cnt[(long)c * MAXNB + i] = hist[i];
    }
    // x -> bf16
    for (long i = tid; i < n4; i += (long)gridDim.x * 256) {
        float4 v = ((const float4*)x)[i];
        ushort4 o;
        o.x = f2bf(v.x); o.y = f2bf(v.y); o.z = f2bf(v.z); o.w = f2bf(v.w);
        ((ushort4*)xb)[i] = o;
    }
}

// ---------------- 2. parallel column scan: wave per bucket ----------------
__global__ __launch_bounds__(512) void k_scanA(int* __restrict__ cnt,   // in-place -> pref
                                               int* __restrict__ btot, int nchunk) {
    int b = (blockIdx.x * 512 + threadIdx.x) >> 6;   // bucket = global wave id
    int lane = threadIdx.x & 63;
    if (b >= MAXNB) return;
    int per = (nchunk + 63) / 64;                    // chunks per lane (<=16 for nchunk<=1024)
    int c0 = lane * per;
    int vals[16];
    int lsum = 0;
#pragma unroll
    for (int i = 0; i < 16; ++i) {
        if (i < per) {
            int c = c0 + i;
            int v = (c < nchunk) ? cnt[(long)c * MAXNB + b] : 0;
            vals[i] = v; lsum += v;
        }
    }
    int incl = lsum;
    for (int off = 1; off < 64; off <<= 1) {
        int o = __shfl_up(incl, off);
        if (lane >= off) incl += o;
    }
    int run = incl - lsum;
#pragma unroll
    for (int i = 0; i < 16; ++i) {
        if (i < per) {
            int c = c0 + i;
            if (c < nchunk) { cnt[(long)c * MAXNB + b] = run; run += vals[i]; }
        }
    }
    int tot = __shfl(incl, 63);
    if (lane == 0) btot[b] = tot;
}

// ---------------- 3. cross-bucket exclusive scan: btot -> bstart (1 block) ----------------
__global__ __launch_bounds__(512) void k_scanB(const int* __restrict__ btot,
                                               int* __restrict__ bstart) {
    __shared__ int wtot[8];
    __shared__ int woff[8];
    int t = threadIdx.x;
    int lane = t & 63, wave = t >> 6;
    int v = btot[t];
    int incl = v;
    for (int off = 1; off < 64; off <<= 1) {
        int o = __shfl_up(incl, off);
        if (lane >= off) incl += o;
    }
    if (lane == 63) wtot[wave] = incl;
    __syncthreads();
    if (t == 0) { int s = 0; for (int i = 0; i < 8; ++i) { woff[i] = s; s += wtot[i]; } }
    __syncthreads();
    bstart[t] = incl - v + woff[wave];
    if (t == 511) bstart[MAXNB] = woff[7] + incl;
}

// ---------------- 4. place edges: single-pass LDS counting sort ----------------
__global__ __launch_bounds__(512) void k_place(const int* __restrict__ src,
                                               const int* __restrict__ dst,
                                               const int* __restrict__ cnt,     // pref
                                               const int* __restrict__ bstart,
                                               unsigned* __restrict__ pay, int n_edges) {
    __shared__ int sbp[MAXNB];       // bstart[b] + pref[b]
    __shared__ int lstart[MAXNB];
    __shared__ int lcur[MAXNB];
    __shared__ unsigned spay[CHP];
    __shared__ int sgpos[CHP];
    __shared__ int wtot[8];
    __shared__ int woff[8];
    int t = threadIdx.x;
    int c = blockIdx.x;
    int e0 = c * CHP, e1 = min(e0 + CHP, n_edges);
    sbp[t] = bstart[t] + cnt[(long)c * MAXNB + t];
    lcur[t] = 0;
    __syncthreads();
    // pass 1: read edges once, capture rank from the histogram atomic
    unsigned rpay[8];
    int rbr[8];                      // (b<<12) | rank, or -1
#pragma unroll
    for (int j = 0; j < 8; ++j) {
        int e = e0 + t + j * 512;
        rbr[j] = -1;
        if (e < e1) {
            int d = dst[e];
            int b = d >> 8;
            int rank = atomicAdd(&lcur[b], 1);
            rpay[j] = ((unsigned)src[e] << 8) | (unsigned)(d & 255);
            rbr[j] = (b << 12) | rank;
        }
    }
    __syncthreads();
    // exclusive scan of lcur (wave-scan + wave-offset combine)
    int lane = t & 63, wave = t >> 6;
    int v = lcur[t];
    int incl = v;
    for (int off = 1; off < 64; off <<= 1) {
        int o = __shfl_up(incl, off);
        if (lane >= off) incl += o;
    }
    if (lane == 63) wtot[wave] = incl;
    __syncthreads();
    if (t == 0) { int s = 0; for (int i = 0; i < 8; ++i) { woff[i] = s; s += wtot[i]; } }
    __syncthreads();
    lstart[t] = incl - v + woff[wave];
    __syncthreads();
    // replay registers into sorted LDS staging
#pragma unroll
    for (int j = 0; j < 8; ++j) {
        if (rbr[j] >= 0) {
            int b = rbr[j] >> 12, rank = rbr[j] & 4095;
            int idx = lstart[b] + rank;
            spay[idx] = rpay[j];
            sgpos[idx] = sbp[b] + rank;
        }
    }
    __syncthreads();
    // linear flush: consecutive i -> consecutive pay positions within runs
    int n = e1 - e0;
    for (int i = t; i < n; i += 512) pay[sgpos[i]] = spay[i];
}

// ---------------- 5. fused aggregate + dual-GEMM (4 blocks/bucket) ----------------
__global__ __launch_bounds__(256) void k_aggemm(const unsigned short* __restrict__ xb,
                                                const unsigned* __restrict__ pay,
                                                const int* __restrict__ bstart,
                                                const unsigned short* __restrict__ WtG,
                                                const float* __restrict__ bias,
                                                float* __restrict__ out,
                                                int num_dst) {
    __shared__ int degs[64];
    __shared__ int rs[64];
    __shared__ int cur[64];
    // union: scsr (gather phase) / W tile (MFMA phase)
    __shared__ __align__(16) unsigned char upool[64 * LDK * 2];   // 17408 B
    __shared__ __align__(16) unsigned short hbt[64 * LDH];        // 64 x 64 means, pad 8
    int* scsr = (int*)upool;
    unsigned short* Wt = (unsigned short*)upool;

    int t = threadIdx.x;
    int blk = blockIdx.x;
    int b = blk >> 2, q = blk & 3;     // bucket, quarter
    int grow0 = b * BROWS + q * 64;
    if (grow0 >= num_dst) return;      // whole block beyond output
    int s0 = bstart[b], s1 = bstart[b + 1];
    int lane = t & 63;
    int wave = t >> 6;

    // --- phase 1: quarter histogram + scan + LDS CSR ---
    if (t < 64) degs[t] = 0;
    __syncthreads();
    for (int i = s0 + t; i < s1; i += 256) {
        int row = pay[i] & 255;
        if ((row >> 6) == q) atomicAdd(&degs[row & 63], 1);
    }
    __syncthreads();
    if (t < 64) {
        int v = degs[t];
        int incl = v;
        for (int off = 1; off < 64; off <<= 1) {
            int o = __shfl_up(incl, off);
            if (t >= off) incl += o;
        }
        rs[t] = incl - v;
        cur[t] = incl - v;
    }
    __syncthreads();
    for (int i = s0 + t; i < s1; i += 256) {
        unsigned p = pay[i];
        int row = p & 255;
        if ((row >> 6) == q) {
            int pos = atomicAdd(&cur[row & 63], 1);
            if (pos < QCAP) scsr[pos] = (int)(p >> 8);
        }
    }
    __syncthreads();

    // --- phase 2: group-per-row gather, 8-deep MLP, means -> hbt ---
    int g = lane >> 3;          // group id = row within batch
    int c8 = (lane & 7) * 8;    // feature octet
#pragma unroll
    for (int batch = 0; batch < 2; ++batch) {
        int rl = wave * 16 + batch * 8 + g;        // 0..63
        int deg = degs[rl];
        int base = rs[rl];
        float acc[8] = {0.f, 0.f, 0.f, 0.f, 0.f, 0.f, 0.f, 0.f};
        for (int k = 0; k < deg; k += 8) {
            int dm = deg - 1;
            int idx[8];
#pragma unroll
            for (int j = 0; j < 8; ++j) idx[j] = scsr[base + min(k + j, dm)];
            short8 u[8];
#pragma unroll
            for (int j = 0; j < 8; ++j) u[j] = *(const short8*)&xb[(long)idx[j] * F + c8];
#pragma unroll
            for (int j = 0; j < 8; ++j) {
                if (k + j < deg) {
#pragma unroll
                    for (int jj = 0; jj < 8; ++jj) acc[jj] += bf2f((unsigned short)u[j][jj]);
                }
            }
        }
        float inv = 1.0f / fmaxf((float)deg, 1.0f);
        short8 o;
#pragma unroll
        for (int j = 0; j < 8; ++j) o[j] = (short)f2bf(acc[j] * inv);
        *(short8*)&hbt[rl * LDH + c8] = o;
    }
    __syncthreads();   // scsr dead, hbt complete

    // --- phase 3: stage W into union, then MFMA ---
    for (int i = t; i < 64 * 16; i += 256) {
        int r = i >> 4, s = i & 15;
        *(short8*)&Wt[r * LDK + s * 8] = *(const short8*)&WtG[r * 128 + s * 8];
    }
    __syncthreads();

    int m = lane & 15;
    int quad = lane >> 4;
    // A fragments: kb 0,1 from xb (global, k 0..63); kb 2,3 from hbt (k 64..127)
    int rowg = grow0 + wave * 16 + m;
    int rx = min(rowg, num_dst - 1);
    const unsigned short* xrow = &xb[(long)rx * F + quad * 8];
    short8 a0 = *(const short8*)(xrow);
    short8 a1 = *(const short8*)(xrow + 32);
    const unsigned short* hrow = &hbt[(wave * 16 + m) * LDH + quad * 8];
    short8 a2 = *(const short8*)(hrow);
    short8 a3 = *(const short8*)(hrow + 32);

    float4v acc[4];
#pragma unroll
    for (int nt = 0; nt < 4; ++nt) acc[nt] = (float4v){0.f, 0.f, 0.f, 0.f};

#pragma unroll
    for (int nt = 0; nt < 4; ++nt) {
        const unsigned short* wrow = &Wt[(nt * 16 + m) * LDK + quad * 8];
        short8 b0 = *(const short8*)(wrow);
        short8 b1 = *(const short8*)(wrow + 32);
        short8 b2 = *(const short8*)(wrow + 64);
        short8 b3 = *(const short8*)(wrow + 96);
        acc[nt] = __builtin_amdgcn_mfma_f32_16x16x32_bf16(a0, b0, acc[nt], 0, 0, 0);
        acc[nt] = __builtin_amdgcn_mfma_f32_16x16x32_bf16(a1, b1, acc[nt], 0, 0, 0);
        acc[nt] = __builtin_amdgcn_mfma_f32_16x16x32_bf16(a2, b2, acc[nt], 0, 0, 0);
        acc[nt] = __builtin_amdgcn_mfma_f32_16x16x32_bf16(a3, b3, acc[nt], 0, 0, 0);
    }

    int gr_base = grow0 + wave * 16 + quad * 4;
#pragma unroll
    for (int nt = 0; nt < 4; ++nt) {
        int col = nt * 16 + m;
        float bv = bias[col];
#pragma unroll
        for (int rg = 0; rg < 4; ++rg) {
            int gg = gr_base + rg;
            if (gg < num_dst) out[(long)gg * F + col] = fmaxf(acc[nt][rg] + bv, 0.0f);
        }
    }
}

// ---------------- fallback (R0, proven) ----------------
__global__ __launch_bounds__(256) void k_scatter(const float* __restrict__ x, const int* __restrict__ src,
                                                 const int* __restrict__ dst, float* __restrict__ summed,
                                                 float* __restrict__ degf, int n_edges) {
    long tid = (long)blockIdx.x * 256 + threadIdx.x;
    int e = (int)(tid >> 6);
    if (e >= n_edges) return;
    int f = threadIdx.x & 63;
    atomicAdd(&summed[(long)dst[e] * F + f], x[(long)src[e] * F + f]);
    if (f == 0) atomicAdd(&degf[dst[e]], 1.0f);
}

__global__ __launch_bounds__(256) void k_gemm_shfl(
    const float* __restrict__ x, const float* __restrict__ Ws, const float* __restrict__ Wn,
    const float* __restrict__ b, const float* __restrict__ degf, float* inout, int num_dst)
{
    __shared__ float Wl[2 * F * F];
    for (int i = threadIdx.x; i < F * F; i += 256) { Wl[i] = Ws[i]; Wl[F * F + i] = Wn[i]; }
    __syncthreads();
    int lane = threadIdx.x & 63;
    int r = (blockIdx.x * 256 + threadIdx.x) >> 6;
    if (r >= num_dst) return;
    float xv = x[(long)r * F + lane];
    float hv = inout[(long)r * F + lane] / fmaxf(degf[r], 1.0f);
    float acc = b[lane];
#pragma unroll
    for (int k = 0; k < F; ++k) {
        acc += __shfl(xv, k) * Wl[k * F + lane];
        acc += __shfl(hv, k) * Wl[(F + k) * F + lane];
    }
    inout[(long)r * F + lane] = fmaxf(acc, 0.0f);
}

// ---------------- launch ----------------
extern "C" void kernel_launch(void* const* d_in, const int* in_sizes, int n_in,
                              void* d_out, int out_size, void* d_ws, size_t ws_size,
                              hipStream_t stream) {
    const float* x  = (const float*)d_in[0];
    const float* Ws = (const float*)d_in[1];
    const float* Wn = (const float*)d_in[2];
    const float* b  = (const float*)d_in[3];
    const int* src  = (const int*)d_in[4];
    const int* dst  = (const int*)d_in[5];
    int n_edges = in_sizes[4];
    int num_dst = out_size / F;
    float* out = (float*)d_out;

    int nchunk = (n_edges + CHP - 1) / CHP;
    int nb = (num_dst + BROWS - 1) / BROWS;

    char* ws = (char*)d_ws;
    size_t off = 0;
    auto alloc = [&](size_t bytes) { char* p = ws + off; off = (off + bytes + 255) & ~(size_t)255; return p; };
    unsigned short* xb  = (unsigned short*)alloc((size_t)num_dst * F * 2);
    unsigned* pay       = (unsigned*)alloc((size_t)n_edges * 4);
    unsigned short* WtG = (unsigned short*)alloc(2 * F * F * 2);
    int* cnt            = (int*)alloc((size_t)nchunk * MAXNB * 4);
    int* btot           = (int*)alloc(MAXNB * 4);
    int* bstart         = (int*)alloc((MAXNB + 1) * 4);
    bool big_ws = (off <= ws_size) && (nb <= MAXNB) && (nchunk <= 1024);

    if (big_ws) {
        long n4 = (long)num_dst * F / 4;
        int convgrid = max(2048, nchunk);
        k_conv<<<convgrid, 256, 0, stream>>>(x, Ws, Wn, xb, WtG, dst, cnt, n4, n_edges, nchunk);
        k_scanA<<<(MAXNB * 64 + 511) / 512, 512, 0, stream>>>(cnt, btot, nchunk);
        k_scanB<<<1, 512, 0, stream>>>(btot, bstart);
        k_place<<<nchunk, 512, 0, stream>>>(src, dst, cnt, bstart, pay, n_edges);
        k_aggemm<<<nb * 4, 256, 0, stream>>>(xb, pay, bstart, WtG, b, out, num_dst);
    } else {
        float* degf = (float*)d_ws;
        (void)hipMemsetAsync(d_out, 0, (size_t)out_size * sizeof(float), stream);
        (void)hipMemsetAsync(degf, 0, (size_t)num_dst * sizeof(float), stream);
        long tt = (long)n_edges * 64;
        k_scatter<<<(int)((tt + 255) / 256), 256, 0, stream>>>(x, src, dst, out, degf, n_edges);
        k_gemm_shfl<<<(num_dst + 3) / 4, 256, 0, stream>>>(x, Ws, Wn, b, degf, out, num_dst);
    }
}